// Round 1
// baseline (1064.927 us; speedup 1.0000x reference)
//
#include <hip/hip_runtime.h>

#define TT 2048
#define BB 512
#define HH 64

// 64-lane full-wave sum via DPP butterfly + scan-bcast; full sum valid in lane 63.
__device__ __forceinline__ float wave_sum_dpp(float v) {
    float t;
    // xor1: quad_perm [1,0,3,2] = 0xB1
    t = __int_as_float(__builtin_amdgcn_update_dpp(0, __float_as_int(v), 0xB1, 0xF, 0xF, false));
    v += t;
    // xor2: quad_perm [2,3,0,1] = 0x4E
    t = __int_as_float(__builtin_amdgcn_update_dpp(0, __float_as_int(v), 0x4E, 0xF, 0xF, false));
    v += t;
    // xor4 (quads uniform -> half_mirror == xor4): 0x141
    t = __int_as_float(__builtin_amdgcn_update_dpp(0, __float_as_int(v), 0x141, 0xF, 0xF, false));
    v += t;
    // xor8 (8-groups uniform -> row_mirror == xor8): 0x140
    t = __int_as_float(__builtin_amdgcn_update_dpp(0, __float_as_int(v), 0x140, 0xF, 0xF, false));
    v += t;
    // row_bcast15: lanes16-31 += lane15, lanes32-47 += lane31, lanes48-63 += lane47
    t = __int_as_float(__builtin_amdgcn_update_dpp(0, __float_as_int(v), 0x142, 0xF, 0xF, false));
    v += t;
    // row_bcast31: lanes32-63 += lane31
    t = __int_as_float(__builtin_amdgcn_update_dpp(0, __float_as_int(v), 0x143, 0xF, 0xF, false));
    v += t;
    return v;  // lane 63 holds the full 64-lane sum
}

__device__ __forceinline__ float bcast_lane(float v, int lane) {
    return __uint_as_float(__builtin_amdgcn_readlane(__float_as_uint(v), lane));
}

__global__ __launch_bounds__(64, 1) void rnn_fused(
    const float* __restrict__ x,     // [T][B]
    const float* __restrict__ h0,    // [B][H]
    const float* __restrict__ Wih,   // [H]
    const float* __restrict__ Whh,   // [H][H]
    const float* __restrict__ bih,   // [H]
    const float* __restrict__ bhh,   // [H]
    const float* __restrict__ Wlin,  // [H]
    const float* __restrict__ blin,  // [1]
    float* __restrict__ y,           // [T][B]
    float* __restrict__ hN)          // [B][H]
{
    const int b = blockIdx.x;   // batch element, 0..511
    const int h = threadIdx.x;  // hidden index (lane), 0..63

    // Per-lane recurrent weight row W_hh[h][0..63] in registers.
    float w[HH];
#pragma unroll
    for (int k = 0; k < HH; k += 4) {
        const float4 v4 = *reinterpret_cast<const float4*>(Whh + h * HH + k);
        w[k + 0] = v4.x; w[k + 1] = v4.y; w[k + 2] = v4.z; w[k + 3] = v4.w;
    }
    const float wih  = Wih[h];
    const float bias = bih[h] + bhh[h];
    const float wlin = Wlin[h];
    const float bl   = blin[0];

    float hval = h0[b * HH + h];

    const float* xb = x + b;  // x[t*BB + b]

    // Prefetch ring, statically indexed (depth 4).
    float xbuf0 = xb[0 * BB];
    float xbuf1 = xb[1 * BB];
    float xbuf2 = xb[2 * BB];
    float xbuf3 = xb[3 * BB];

#pragma unroll 1
    for (int t = 0; t < TT; t += 4) {
#pragma unroll
        for (int u = 0; u < 4; ++u) {
            const int tt = t + u;
            float xt;
            if (u == 0) xt = xbuf0;
            else if (u == 1) xt = xbuf1;
            else if (u == 2) xt = xbuf2;
            else xt = xbuf3;
            const int tn = tt + 4;
            if (tn < TT) {
                const float xl = xb[tn * BB];
                if (u == 0) xbuf0 = xl;
                else if (u == 1) xbuf1 = xl;
                else if (u == 2) xbuf2 = xl;
                else xbuf3 = xl;
            }

            // dot(h_prev, W_hh[h][:]) via readlane broadcast, 4 indep chains
            float a0 = 0.f, a1 = 0.f, a2 = 0.f, a3 = 0.f;
#pragma unroll
            for (int k = 0; k < HH; k += 4) {
                a0 = fmaf(bcast_lane(hval, k + 0), w[k + 0], a0);
                a1 = fmaf(bcast_lane(hval, k + 1), w[k + 1], a1);
                a2 = fmaf(bcast_lane(hval, k + 2), w[k + 2], a2);
                a3 = fmaf(bcast_lane(hval, k + 3), w[k + 3], a3);
            }
            const float acc = fmaf(xt, wih, bias) + ((a0 + a1) + (a2 + a3));

            // tanh(acc) = 1 - 2/(e^{2acc}+1); saturates correctly for |acc| large
            const float e2 = __expf(acc + acc);
            hval = 1.0f - __fdividef(2.0f, e2 + 1.0f);

            // y[tt][b] = sum_h hval*wlin + b_lin  (reduce off the critical path)
            float s = wave_sum_dpp(hval * wlin);
            if (h == 63) {
                y[tt * BB + b] = s + bl;
            }
        }
    }

    hN[b * HH + h] = hval;
}

extern "C" void kernel_launch(void* const* d_in, const int* in_sizes, int n_in,
                              void* d_out, int out_size, void* d_ws, size_t ws_size,
                              hipStream_t stream) {
    const float* x    = (const float*)d_in[0];
    const float* h0   = (const float*)d_in[1];
    const float* Wih  = (const float*)d_in[2];
    const float* Whh  = (const float*)d_in[3];
    const float* bih  = (const float*)d_in[4];
    const float* bhh  = (const float*)d_in[5];
    const float* Wlin = (const float*)d_in[6];
    const float* blin = (const float*)d_in[7];

    float* y  = (float*)d_out;            // [T*B]
    float* hN = (float*)d_out + TT * BB;  // [B*H]

    rnn_fused<<<dim3(BB), dim3(HH), 0, stream>>>(x, h0, Wih, Whh, bih, bhh, Wlin, blin, y, hN);
}